// Round 1
// baseline (2998.540 us; speedup 1.0000x reference)
//
#include <hip/hip_runtime.h>
#include <hip/hip_bf16.h>
#include <math.h>

#define Bn 8
#define Tn 1024
#define Nn 64
#define Hn 128
#define G4 512   // 4*H
#define WIDTHn 32
#define INPn 64

__device__ __forceinline__ float sigmoidf_(float x) {
    return 1.0f / (1.0f + __expf(-x));
}
__device__ __forceinline__ float tanhf_(float x) {
    float e = __expf(-2.0f * fabsf(x));
    float t = (1.0f - e) / (1.0f + e);
    return copysignf(t, x);
}

__global__ __launch_bounds__(512) void lstm_fused(
    const float* __restrict__ spikes,
    const float* __restrict__ enc,
    const float* __restrict__ W_ih,
    const float* __restrict__ W_hh,
    const float* __restrict__ b_ih,
    const float* __restrict__ b_hh,
    float* __restrict__ out)
{
    const int t = threadIdx.x;       // 0..511 == gate row g
    const int bn = blockIdx.x;
    const int n = bn & (Nn - 1);
    const int b = bn >> 6;

    __shared__ __align__(16) float xenc[INPn];
    __shared__ __align__(16) float h_lds[Hn];
    __shared__ __align__(16) float gates[G4];
    __shared__ float sp_lds[Tn];

    // stage this cell's spike train (stride-N gather, one-time)
    for (int i = t; i < Tn; i += 512)
        sp_lds[i] = spikes[(size_t)(b * Tn + i) * Nn + n];
    if (t < Hn) h_lds[t] = 0.0f;

    // per-thread weights resident in VGPRs
    float4 wih[INPn / 4];
    float4 whh[Hn / 4];
    {
        const float4* p = reinterpret_cast<const float4*>(W_ih + ((size_t)n * G4 + t) * INPn);
        #pragma unroll
        for (int i = 0; i < INPn / 4; ++i) wih[i] = p[i];
        const float4* q = reinterpret_cast<const float4*>(W_hh + ((size_t)n * G4 + t) * Hn);
        #pragma unroll
        for (int i = 0; i < Hn / 4; ++i) whh[i] = q[i];
    }
    const float bias = b_ih[n * G4 + t] + b_hh[n * G4 + t];
    const bool is_g = (t >= 2 * Hn) && (t < 3 * Hn);   // PyTorch order i,f,g,o
    const float my_w = (t < WIDTHn) ? enc[t] : 0.0f;

    float c = 0.0f;
    size_t outbase = ((size_t)b * Tn * Nn + n) * Hn;

    __syncthreads();

    for (int step = 0; step < Tn; ++step) {
        if (t < WIDTHn) {
            float x = 2.0f * sp_lds[step] - 1.0f;
            float ang = 6.283185307179586f * my_w * x;
            xenc[t] = cosf(ang);
            xenc[t + WIDTHn] = sinf(ang);
        }
        __syncthreads();

        float a0 = 0.f, a1 = 0.f, a2 = 0.f, a3 = 0.f;
        const float4* xe4 = reinterpret_cast<const float4*>(xenc);
        #pragma unroll
        for (int i = 0; i < INPn / 4; ++i) {
            float4 v = xe4[i];
            a0 = fmaf(wih[i].x, v.x, a0);
            a1 = fmaf(wih[i].y, v.y, a1);
            a2 = fmaf(wih[i].z, v.z, a2);
            a3 = fmaf(wih[i].w, v.w, a3);
        }
        const float4* h4 = reinterpret_cast<const float4*>(h_lds);
        #pragma unroll
        for (int k = 0; k < Hn / 4; ++k) {
            float4 v = h4[k];
            a0 = fmaf(whh[k].x, v.x, a0);
            a1 = fmaf(whh[k].y, v.y, a1);
            a2 = fmaf(whh[k].z, v.z, a2);
            a3 = fmaf(whh[k].w, v.w, a3);
        }
        float acc = bias + ((a0 + a1) + (a2 + a3));
        gates[t] = is_g ? tanhf_(acc) : sigmoidf_(acc);
        __syncthreads();

        if (t < Hn) {
            float gi = gates[t];
            float gf = gates[Hn + t];
            float gg = gates[2 * Hn + t];
            float go = gates[3 * Hn + t];
            c = fmaf(gf, c, gi * gg);
            float hn = go * tanhf_(c);
            h_lds[t] = hn;
            out[outbase + t] = hn;
        }
        __syncthreads();
        outbase += (size_t)Nn * Hn;
    }
}

extern "C" void kernel_launch(void* const* d_in, const int* in_sizes, int n_in,
                              void* d_out, int out_size, void* d_ws, size_t ws_size,
                              hipStream_t stream) {
    const float* spikes = (const float*)d_in[0];
    const float* enc    = (const float*)d_in[1];
    const float* W_ih   = (const float*)d_in[2];
    const float* W_hh   = (const float*)d_in[3];
    const float* b_ih   = (const float*)d_in[4];
    const float* b_hh   = (const float*)d_in[5];
    float* out = (float*)d_out;

    dim3 grid(Bn * Nn);
    dim3 block(512);
    hipLaunchKernelGGL(lstm_fused, grid, block, 0, stream,
                       spikes, enc, W_ih, W_hh, b_ih, b_hh, out);
}

// Round 2
// 1332.495 us; speedup vs baseline: 2.2503x; 2.2503x over previous
//
#include <hip/hip_runtime.h>
#include <math.h>

#define Bv 8
#define Tv 1024
#define Nv 64
#define Hv 128
#define WIDTHv 32
#define ZP 216   // bf16 k-pitch per batch-col: 192 used, padded to 216 (16B-aligned, bank-spread)

typedef float  f32x4  __attribute__((ext_vector_type(4)));
typedef short  bf16x8 __attribute__((ext_vector_type(8)));
typedef short  bf16x4 __attribute__((ext_vector_type(4)));

__device__ __forceinline__ short f2bf(float f) {
    union { float f; unsigned u; } v; v.f = f;
    return (short)((v.u + 0x7FFFu + ((v.u >> 16) & 1u)) >> 16);  // RNE fp32->bf16
}
__device__ __forceinline__ float sigm(float x) {
    return __builtin_amdgcn_rcpf(1.0f + __expf(-x));
}
__device__ __forceinline__ float tanhfast(float x) {
    float e = __expf(-2.0f * __builtin_fabsf(x));
    float t = (1.0f - e) * __builtin_amdgcn_rcpf(1.0f + e);
    return __builtin_copysignf(t, x);
}

// One block per neuron n. 512 threads = 8 waves.
// Wave w owns h-rows [16w, 16w+16): computes gate rows {128g + 16w + 0..15} for g=i,f,g,o.
// MFMA 16x16x32 bf16: A = W tile (M=gate rows, K), B = z tile (K, N=batch cols; 8 valid).
// After MFMA, lane l holds pre-acts for h-rows 16w+4*(l>>4)+{0..3}, batch col l&15
// -> in-lane activation + c/h update, no cross-lane traffic.
__global__ __launch_bounds__(512, 2) void lstm_mfma(
    const float* __restrict__ spikes,
    const float* __restrict__ enc,
    const float* __restrict__ W_ih,
    const float* __restrict__ W_hh,
    const float* __restrict__ b_ih,
    const float* __restrict__ b_hh,
    float* __restrict__ out)
{
    const int tid = threadIdx.x;
    const int n   = blockIdx.x;
    const int w   = tid >> 6;
    const int l   = tid & 63;
    const int col = l & 15;          // batch col (valid < 8)
    const int q   = l >> 4;          // k-group 0..3
    const bool active = (col < 8);
    const int cc  = col & 7;         // clamped for safe LDS addressing

    // z = [cos(ang) k=0..31 | sin(ang) k=32..63 | h k=64..191], bf16, per batch col.
    __shared__ short zT[2][8][ZP];   // double-buffered, ~6.9 KB

    // ---- one-time: weights -> bf16 A-fragments in VGPRs (96 VGPRs) ----
    bf16x8 afrag[4][6];
    #pragma unroll
    for (int g = 0; g < 4; ++g) {
        const int grow = 128 * g + 16 * w + col;   // A-fragment row = lane&15 within tile
        #pragma unroll
        for (int kt = 0; kt < 6; ++kt) {
            const float* src = (kt < 2)
                ? (W_ih + ((size_t)(n * 512 + grow)) * 64  + kt * 32 + q * 8)
                : (W_hh + ((size_t)(n * 512 + grow)) * 128 + (kt - 2) * 32 + q * 8);
            float4 u0 = *(const float4*)(src);
            float4 u1 = *(const float4*)(src + 4);
            bf16x8 a;
            a[0] = f2bf(u0.x); a[1] = f2bf(u0.y); a[2] = f2bf(u0.z); a[3] = f2bf(u0.w);
            a[4] = f2bf(u1.x); a[5] = f2bf(u1.y); a[6] = f2bf(u1.z); a[7] = f2bf(u1.w);
            afrag[g][kt] = a;
        }
    }

    // bias folded into accumulator init: C/D row = (l>>4)*4 + reg
    f32x4 bias4[4];
    #pragma unroll
    for (int g = 0; g < 4; ++g) {
        #pragma unroll
        for (int r = 0; r < 4; ++r) {
            const int brow = 128 * g + 16 * w + 4 * q + r;
            bias4[g][r] = b_ih[n * 512 + brow] + b_hh[n * 512 + brow];
        }
    }

    // fourier-encoding ownership: threads 0..255 -> (batch xb, freq xi)
    const bool isx = (tid < 256);
    const int  xb  = tid >> 5, xi = tid & 31;
    const float encv = isx ? enc[xi] : 0.0f;

    // ---- prologue: xenc(step 0) + zero h into buffer 0 ----
    if (isx) {
        float sp  = spikes[((size_t)xb * Tv + 0) * Nv + n];
        float ang = 6.283185307179586f * encv * (2.0f * sp - 1.0f);
        float s, c;
        __sincosf(ang, &s, &c);
        zT[0][xb][xi]          = f2bf(c);
        zT[0][xb][WIDTHv + xi] = f2bf(s);
    }
    {
        const int c0 = tid >> 6, k0 = 64 + (tid & 63);
        zT[0][c0][k0]      = 0;
        zT[0][c0][k0 + 64] = 0;
    }
    float cst[4] = {0.0f, 0.0f, 0.0f, 0.0f};
    __syncthreads();

    const size_t outrow = ((size_t)cc * Tv) * (size_t)(Nv * Hv) + (size_t)n * Hv + 16 * w + 4 * q;

    for (int step = 0; step < Tv; ++step) {
        const int cur = step & 1, nxt = cur ^ 1;

        // prefetch next spike early (hides under MFMA+update)
        float spn = 0.0f;
        if (isx) {
            const int s1 = (step + 1 < Tv) ? step + 1 : Tv - 1;
            spn = spikes[((size_t)xb * Tv + s1) * Nv + n];
        }

        // B fragments: z[k, col] contiguous-8-k per lane-group (same map as A)
        bf16x8 bfrag[6];
        #pragma unroll
        for (int kt = 0; kt < 6; ++kt) {
            bf16x8 v = *(const bf16x8*)&zT[cur][cc][kt * 32 + q * 8];
            if (!active) v = (bf16x8){0, 0, 0, 0, 0, 0, 0, 0};
            bfrag[kt] = v;
        }

        // gates = W * z + bias
        f32x4 acc[4];
        #pragma unroll
        for (int g = 0; g < 4; ++g) {
            acc[g] = bias4[g];
            #pragma unroll
            for (int kt = 0; kt < 6; ++kt)
                acc[g] = __builtin_amdgcn_mfma_f32_16x16x32_bf16(
                             afrag[g][kt], bfrag[kt], acc[g], 0, 0, 0);
        }

        // in-lane LSTM update for 4 h-rows
        float hr[4];
        #pragma unroll
        for (int r = 0; r < 4; ++r) {
            float gi = sigm(acc[0][r]);
            float gf = sigm(acc[1][r]);
            float gg = tanhfast(acc[2][r]);
            float go = sigm(acc[3][r]);
            float cv = gf * cst[r] + gi * gg;
            cst[r] = cv;
            hr[r] = go * tanhfast(cv);
        }

        if (active) {
            bf16x4 hb;
            hb[0] = f2bf(hr[0]); hb[1] = f2bf(hr[1]);
            hb[2] = f2bf(hr[2]); hb[3] = f2bf(hr[3]);
            *(bf16x4*)&zT[nxt][cc][64 + 16 * w + 4 * q] = hb;

            float4 ho;
            ho.x = hr[0]; ho.y = hr[1]; ho.z = hr[2]; ho.w = hr[3];
            *(float4*)(out + outrow + (size_t)step * (Nv * Hv)) = ho;
        }

        // encoding for step+1
        if (isx) {
            float ang = 6.283185307179586f * encv * (2.0f * spn - 1.0f);
            float s, c;
            __sincosf(ang, &s, &c);
            zT[nxt][xb][xi]          = f2bf(c);
            zT[nxt][xb][WIDTHv + xi] = f2bf(s);
        }

        __syncthreads();
    }
}

extern "C" void kernel_launch(void* const* d_in, const int* in_sizes, int n_in,
                              void* d_out, int out_size, void* d_ws, size_t ws_size,
                              hipStream_t stream) {
    (void)in_sizes; (void)n_in; (void)ws_size; (void)d_ws;
    const float* spikes = (const float*)d_in[0];
    const float* enc    = (const float*)d_in[1];
    const float* W_ih   = (const float*)d_in[2];
    const float* W_hh   = (const float*)d_in[3];
    const float* b_ih   = (const float*)d_in[4];
    const float* b_hh   = (const float*)d_in[5];
    float* out = (float*)d_out;

    hipLaunchKernelGGL(lstm_mfma, dim3(Nv), dim3(512), 0, stream,
                       spikes, enc, W_ih, W_hh, b_ih, b_hh, out);
}